// Round 2
// 176.574 us; speedup vs baseline: 1.0014x; 1.0014x over previous
//
#include <hip/hip_runtime.h>
#include <cmath>

#define ENTRIES 27
#define ACTION  4096
#define BATCH   8192
#define SDIM    322
#define KPAD    352      // 322 padded to multiple of 32
#define NNODES  256

typedef unsigned short u16;
typedef u16 u16x4 __attribute__((ext_vector_type(4)));
typedef u16 u16x8 __attribute__((ext_vector_type(8)));
typedef __bf16 bf16x8 __attribute__((ext_vector_type(8)));
typedef float floatx2 __attribute__((ext_vector_type(2)));
typedef float floatx4 __attribute__((ext_vector_type(4)));

__device__ __forceinline__ u16 f2bf(float f) {
    unsigned u = __builtin_bit_cast(unsigned, f);
    unsigned r = (u + 0x7FFFu + ((u >> 16) & 1u)) >> 16;   // RNE
    return (u16)r;
}
__device__ __forceinline__ float sig500(float v) {
    return __fdividef(500.0f, 1.0f + __expf(-v));
}
__device__ __forceinline__ float ftanh(float x) {
    return 1.0f - __fdividef(2.0f, __expf(2.0f * x) + 1.0f);
}
// async global->LDS, 16 B per lane; LDS dest = wave-uniform base + lane*16
__device__ __forceinline__ void gl_lds16(const u16* g, u16* l) {
    __builtin_amdgcn_global_load_lds(
        (const __attribute__((address_space(1))) unsigned int*)g,
        (__attribute__((address_space(3))) unsigned int*)l, 16, 0, 0);
}

// ---------------------------------------------------------------------------
// Prep (shrunk): blocks [0,32): Wg[256,KPAD] bf16 scatter-build (8 nodes/blk)
//                blocks [32,1056): Wf f32[4096,256] -> bf16
// (state conversion is fused into gemm1's A-staging)
// ---------------------------------------------------------------------------
#define PREP_WF0 32
#define PREP_TOT 1056

__global__ __launch_bounds__(256) void prep_kernel(
    const float* __restrict__ W, const int* __restrict__ idx,
    const float* __restrict__ wf,
    u16* __restrict__ wg, u16* __restrict__ wfb)
{
    const int tid = threadIdx.x;
    const int bid = blockIdx.x;

    if (bid < PREP_WF0) {
        __shared__ float rows[8 * KPAD];               // 11264 B
        for (int i = tid; i < 8 * KPAD; i += 256) rows[i] = 0.f;
        __syncthreads();
        if (tid < 8 * ENTRIES) {                       // 216 active
            const int nl = tid / ENTRIES;
            const int e  = tid - nl * ENTRIES;
            const int n  = bid * 8 + nl;
            atomicAdd(&rows[nl * KPAD + idx[n * ENTRIES + e]],
                      W[n * ENTRIES + e]);
        }
        __syncthreads();
        for (int i = tid; i < 8 * KPAD; i += 256)
            wg[(size_t)bid * 8 * KPAD + i] = f2bf(rows[i]);
    } else {
        const int i0 = ((bid - PREP_WF0) * 256 + tid) * 4;
        floatx4 v = *(const floatx4*)(wf + i0);
        u16x4 r;
        r.x = f2bf(v.x); r.y = f2bf(v.y); r.z = f2bf(v.z); r.w = f2bf(v.w);
        *(u16x4*)(wfb + i0) = r;
    }
}

// ---------------------------------------------------------------------------
// gemm1 fused: y[b,n] = tanh( state[b,:322] . WgT[n] + bias[n] ), bf16 out.
//  - A = state f32, converted to bf16 in registers during staging
//    (loads issued after the MFMA phase starts; consumed by cvt next
//     iteration -> HBM latency hidden under MFMA, never drained at a barrier)
//  - B = Wg slice [64 x KPAD] bf16, LDS-RESIDENT (one prologue stage)
//  - BM=64 -> grid (128,4) = 512 blocks = 2 blocks/CU for stall overlap
// ---------------------------------------------------------------------------
__global__ __launch_bounds__(256) void gemm1_fused(
    const float* __restrict__ state, const u16* __restrict__ wg,
    u16* __restrict__ y, const float* __restrict__ bias)
{
    __shared__ u16 Bs[64 * KPAD];   // 45056 B, resident the whole loop
    __shared__ u16 As[64 * 32];     // 4096 B, one K-step

    const int bm   = blockIdx.x;    // 128 tiles of 64 rows
    const int bn   = blockIdx.y;    // 4 tiles of 64 nodes
    const int tid  = threadIdx.x;
    const int lane = tid & 63;
    const int wave = tid >> 6;
    const int wm   = wave & 1;      // 2x2 waves, each 32x32
    const int wn   = wave >> 1;
    const int l15  = lane & 15;
    const int koff = (lane >> 4) << 3;

    // ---- prologue: stage resident B (44 KiB contiguous) ----
    const u16* wgp = wg + (size_t)bn * 64 * KPAD;
    for (int c = wave; c < 44; c += 4)
        gl_lds16(wgp + c * 512 + lane * 8, &Bs[c * 512]);

    // ---- A register prefetch: thread -> (row = tid>>2, 8 cols) ----
    const int arow = tid >> 2;             // 0..63
    const int qseg = tid & 3;              // which 8-col group
    const float* ap = state + (size_t)(bm * 64 + arow) * SDIM + qseg * 8;
    float va[8];

    auto loada = [&](int kk) {
        const int c0 = kk + qseg * 8;
        const float* p = ap + kk;
        if (c0 + 8 <= SDIM) {
#pragma unroll
            for (int j = 0; j < 4; j++)
                *(floatx2*)&va[2 * j] = *(const floatx2*)(p + 2 * j);
        } else {
#pragma unroll
            for (int j = 0; j < 8; j++)
                va[j] = (c0 + j < SDIM) ? p[j] : 0.f;   // zero-pad 322..351
        }
    };
    loada(0);

    floatx4 acc[2][2];
#pragma unroll
    for (int mi = 0; mi < 2; mi++)
#pragma unroll
        for (int ni = 0; ni < 2; ni++)
            acc[mi][ni] = (floatx4){0.f, 0.f, 0.f, 0.f};

#pragma unroll
    for (int s = 0; s < 11; s++) {
        const int kk = s * 32;
        // convert the prefetched A chunk (s_waitcnt on the loads lands HERE,
        // after a full MFMA phase of overlap — not at a barrier)
        u16x8 pk;
#pragma unroll
        for (int j = 0; j < 8; j++) ((u16*)&pk)[j] = f2bf(va[j]);

        __syncthreads();                       // prev iter's ds_reads done
        *(u16x8*)&As[arow * 32 + qseg * 8] = pk;
        __syncthreads();                       // As(k) visible to all waves

        if (s < 10) loada(kk + 32);            // issue next loads under MFMA

        bf16x8 af[2], bfr[2];
#pragma unroll
        for (int mi = 0; mi < 2; mi++)
            af[mi] = __builtin_bit_cast(bf16x8,
                *(const u16x8*)&As[((wm << 5) + (mi << 4) + l15) * 32 + koff]);
#pragma unroll
        for (int ni = 0; ni < 2; ni++)
            bfr[ni] = __builtin_bit_cast(bf16x8,
                *(const u16x8*)&Bs[(wn * 32 + ni * 16 + l15) * KPAD + kk + koff]);
#pragma unroll
        for (int mi = 0; mi < 2; mi++)
#pragma unroll
            for (int ni = 0; ni < 2; ni++)
                acc[mi][ni] = __builtin_amdgcn_mfma_f32_16x16x32_bf16(
                    af[mi], bfr[ni], acc[mi][ni], 0, 0, 0);
    }

    // epilogue: C/D layout col=lane&15, row=(lane>>4)*4+reg
    const int r0 = (lane >> 4) << 2;
    float bv[2];
#pragma unroll
    for (int ni = 0; ni < 2; ni++)
        bv[ni] = bias[bn * 64 + wn * 32 + ni * 16 + l15];
#pragma unroll
    for (int mi = 0; mi < 2; mi++)
#pragma unroll
        for (int ni = 0; ni < 2; ni++) {
            const int row = bm * 64 + wm * 32 + mi * 16 + r0;
            const int col = bn * 64 + wn * 32 + ni * 16 + l15;
#pragma unroll
            for (int r = 0; r < 4; r++)
                y[(size_t)(row + r) * NNODES + col] =
                    f2bf(ftanh(acc[mi][ni][r] + bv[ni]));
        }
}

// ---------------------------------------------------------------------------
// gemm2 (known-good m97 structure): out = 500*sigmoid(y . WfT)
// Tile 128x128, BK=32, 4 waves 2x2, mfma_f32_16x16x32_bf16,
// global_load_lds width-16 staging. Write-bound: 134 MB f32 output.
// ---------------------------------------------------------------------------
template<int KDIM, int EPI, int BN>
__global__ __launch_bounds__(256) void gemm_mfma(
    const u16* __restrict__ A, const u16* __restrict__ B,
    void* __restrict__ outp, const float* __restrict__ bias)
{
    constexpr int NI  = BN / 32;
    constexpr int WN  = BN / 2;
    constexpr int ACH = 8;
    constexpr int BCH = BN / 16;

    __shared__ u16 As[128 * 32];
    __shared__ u16 Bs[BN * 32];

    const int bm   = blockIdx.x;
    const int bn   = blockIdx.y;
    const int tid  = threadIdx.x;
    const int lane = tid & 63;
    const int wave = tid >> 6;
    const int wm   = wave & 1;
    const int wn   = wave >> 1;
    const int l15  = lane & 15;
    const int koff = (lane >> 4) << 3;

    floatx4 acc[4][NI];
#pragma unroll
    for (int mi = 0; mi < 4; mi++)
#pragma unroll
        for (int ni = 0; ni < NI; ni++)
            acc[mi][ni] = (floatx4){0.f, 0.f, 0.f, 0.f};

    const int crow = lane >> 2;
    const int ckel = (lane & 3) << 3;

#pragma unroll
    for (int kk = 0; kk < KDIM; kk += 32) {
        __syncthreads();
#pragma unroll
        for (int c = wave; c < ACH + BCH; c += 4) {
            const bool isA = c < ACH;
            const int  cr  = isA ? c : c - ACH;
            const int  row = cr * 16 + crow;
            const u16* g = isA
                ? (A + ((size_t)bm * 128 + row) * KDIM + kk + ckel)
                : (B + ((size_t)bn * BN  + row) * KDIM + kk + ckel);
            u16* l = isA ? &As[cr * 512] : &Bs[cr * 512];
            gl_lds16(g, l);
        }
        __syncthreads();

        bf16x8 af[4], bfg[NI];
#pragma unroll
        for (int mi = 0; mi < 4; mi++)
            af[mi] = __builtin_bit_cast(bf16x8,
                *(const u16x8*)&As[((wm << 6) + (mi << 4) + l15) * 32 + koff]);
#pragma unroll
        for (int ni = 0; ni < NI; ni++)
            bfg[ni] = __builtin_bit_cast(bf16x8,
                *(const u16x8*)&Bs[(wn * WN + (ni << 4) + l15) * 32 + koff]);

#pragma unroll
        for (int mi = 0; mi < 4; mi++)
#pragma unroll
            for (int ni = 0; ni < NI; ni++)
                acc[mi][ni] = __builtin_amdgcn_mfma_f32_16x16x32_bf16(
                    af[mi], bfg[ni], acc[mi][ni], 0, 0, 0);
    }

    const int r0 = (lane >> 4) << 2;
    float bv[NI];
    if (EPI == 1) {
#pragma unroll
        for (int ni = 0; ni < NI; ni++)
            bv[ni] = bias[bn * BN + wn * WN + ni * 16 + l15];
    }
#pragma unroll
    for (int mi = 0; mi < 4; mi++) {
#pragma unroll
        for (int ni = 0; ni < NI; ni++) {
            const int row = bm * 128 + wm * 64 + mi * 16 + r0;
            const int col = bn * BN + wn * WN + ni * 16 + l15;
#pragma unroll
            for (int r = 0; r < 4; r++) {
                float v = acc[mi][ni][r];
                if (EPI == 0) {
                    ((float*)outp)[(size_t)(row + r) * ACTION + col] = sig500(v);
                } else {
                    ((u16*)outp)[(size_t)(row + r) * NNODES + col] =
                        f2bf(ftanh(v + bv[ni]));
                }
            }
        }
    }
}

extern "C" void kernel_launch(void* const* d_in, const int* in_sizes, int n_in,
                              void* d_out, int out_size, void* d_ws, size_t ws_size,
                              hipStream_t stream) {
    const float* state = (const float*)d_in[0];
    const float* W     = (const float*)d_in[1];
    const float* b     = (const float*)d_in[2];
    const float* Wf    = (const float*)d_in[3];
    const int*   idx   = (const int*)  d_in[4];
    float* out = (float*)d_out;

    u16* wg  = (u16*)d_ws;                         // 256*352 bf16
    u16* y   = wg + (size_t)NNODES * KPAD;         // 8192*256 bf16
    u16* wfb = y  + (size_t)BATCH * NNODES;        // 4096*256 bf16

    prep_kernel<<<PREP_TOT, 256, 0, stream>>>(W, idx, Wf, wg, wfb);
    gemm1_fused<<<dim3(128, 4), 256, 0, stream>>>(state, wg, y, b);
    gemm_mfma<256, 0, 128><<<dim3(BATCH / 128, ACTION / 128), 256, 0, stream>>>(
        y, wfb, (void*)out, nullptr);
}